// Round 2
// baseline (576.636 us; speedup 1.0000x reference)
//
#include <hip/hip_runtime.h>

// Problem constants (from reference)
#define DH   66          // decoder hidden
#define GK   264         // 4*DH gate rows (torch order i,f,g,o)
#define HP   68          // h padded to float4 multiple
#define EMB  128
#define TSTEPS 512
#define BATCH 128
#define REGION (TSTEPS*DH)   // 33792 floats per batch row

// ---------------------------------------------------------------------------
// Kernel 1: fold fc layer into recurrent weights.
//   Wc[k][j] = sum_e Wih[k][e]*fcW[e][j] + Whh[k][j]    (j<66; j=66,67 -> 0)
//   bc[k]    = sum_e Wih[k][e]*fcb[e] + bih[k]+bhh[k]
//   g0[k]    = sum_e Wih[k][e]*emb0[e] + bih[k]+bhh[k]   (step-0 gates)
// ---------------------------------------------------------------------------
__global__ void fold_weights(const float* __restrict__ Wih,   // [264][128]
                             const float* __restrict__ Whh,   // [264][66]
                             const float* __restrict__ bih,   // [264]
                             const float* __restrict__ bhh,   // [264]
                             const float* __restrict__ fcW,   // [128][66]
                             const float* __restrict__ fcb,   // [128]
                             const float* __restrict__ emb0,  // [128] row 0 of emb
                             float* __restrict__ Wc,          // [264][68]
                             float* __restrict__ bc,          // [264]
                             float* __restrict__ g0) {        // [264]
    __shared__ float a[EMB];
    const int k = blockIdx.x;
    const int j = threadIdx.x;
    if (j < EMB) a[j] = Wih[k * EMB + j];
    __syncthreads();
    if (j < DH) {
        float acc = Whh[k * DH + j];
        #pragma unroll 8
        for (int e = 0; e < EMB; ++e) acc = fmaf(a[e], fcW[e * DH + j], acc);
        Wc[k * HP + j] = acc;
    } else if (j == DH) {
        Wc[k * HP + DH] = 0.f;
        float acc = bih[k] + bhh[k];
        #pragma unroll 8
        for (int e = 0; e < EMB; ++e) acc = fmaf(a[e], fcb[e], acc);
        bc[k] = acc;
    } else if (j == DH + 1) {
        Wc[k * HP + DH + 1] = 0.f;
        float acc = bih[k] + bhh[k];
        #pragma unroll 8
        for (int e = 0; e < EMB; ++e) acc = fmaf(a[e], emb0[e], acc);
        g0[k] = acc;
    }
}

// ---------------------------------------------------------------------------
// Kernel 2: the sequential 512-step decoder chain. One block, 5 waves.
//   phase B (66 threads): gates -> (i,f,g,o) -> c,h update; h -> LDS + out[b=0]
//   phase A (264 threads): g[k] = bc[k] + dot(Wc_row_k (regs), h (LDS b128))
// ---------------------------------------------------------------------------
__device__ __forceinline__ float sig_(float x)  { return 1.f / (1.f + __expf(-x)); }
__device__ __forceinline__ float tanh_(float x) { return 2.f / (1.f + __expf(-2.f * x)) - 1.f; }

__global__ __launch_bounds__(320, 1)
void decode_seq(const float* __restrict__ Wc,
                const float* __restrict__ bc,
                const float* __restrict__ g0,
                float* __restrict__ hseq) {          // out region b=0: [512][66]
    __shared__ __align__(16) float h_s[HP];
    __shared__ float g_s[GK];
    const int t = threadIdx.x;

    float4 w[HP / 4];
    float bcm = 0.f;
    if (t < GK) {
        const float4* row = reinterpret_cast<const float4*>(Wc + t * HP);
        #pragma unroll
        for (int i = 0; i < HP / 4; ++i) w[i] = row[i];
        bcm = bc[t];
        g_s[t] = g0[t];                 // step-0 gates precomputed on emb[0]
    }
    if (t < HP) h_s[t] = 0.f;           // zero h + padding
    float c = 0.f;
    __syncthreads();

    for (int step = 0; ; ++step) {
        // ---- phase B: cell update (threads 0..65) ----
        if (t < DH) {
            const float gi = g_s[t];
            const float gf = g_s[DH + t];
            const float gg = g_s[2 * DH + t];
            const float go = g_s[3 * DH + t];
            const float iv = sig_(gi);
            const float fv = sig_(gf);
            const float gv = tanh_(gg);
            const float ov = sig_(go);
            c = fmaf(fv, c, iv * gv);
            const float h = ov * tanh_(c);
            h_s[t] = h;
            hseq[step * DH + t] = h;    // fire-and-forget global store
        }
        if (step == TSTEPS - 1) break;  // uniform across all threads
        __syncthreads();

        // ---- phase A: next-step gates (threads 0..263) ----
        if (t < GK) {
            const float4* h4 = reinterpret_cast<const float4*>(h_s);
            float ax = bcm, ay = 0.f, az = 0.f, aw = 0.f;
            #pragma unroll
            for (int i = 0; i < HP / 4; ++i) {
                const float4 hv = h4[i];    // ds_read_b128, broadcast (same addr)
                ax = fmaf(w[i].x, hv.x, ax);
                ay = fmaf(w[i].y, hv.y, ay);
                az = fmaf(w[i].z, hv.z, az);
                aw = fmaf(w[i].w, hv.w, aw);
            }
            g_s[t] = (ax + ay) + (az + aw);
        }
        __syncthreads();
    }
}

// ---------------------------------------------------------------------------
// Kernel 3: broadcast batch-0 region to b=1..127 (float4 copy, 17.2 MB write)
// grid = 127*8 blocks; region = 8448 float4 = 8 tiles of 1056
// ---------------------------------------------------------------------------
__global__ void bcast_out(const float4* src_base, float4* dst_base) {
    const int TILE = 1056;
    const float4* src = src_base + (blockIdx.x & 7) * TILE;
    float4* dst = dst_base + (size_t)(blockIdx.x + 8) * TILE;   // skip b=0 (8 tiles)
    #pragma unroll 2
    for (int i = threadIdx.x; i < TILE; i += 256) dst[i] = src[i];
}

// ---------------------------------------------------------------------------
extern "C" void kernel_launch(void* const* d_in, const int* in_sizes, int n_in,
                              void* d_out, int out_size, void* d_ws, size_t ws_size,
                              hipStream_t stream) {
    // setup_inputs order:
    // 0:x 1:c 2:emb 3:enc_W_ih 4:enc_W_hh 5:enc_b_ih 6:enc_b_hh
    // 7:dec_W_ih 8:dec_W_hh 9:dec_b_ih 10:dec_b_hh 11:fc_W 12:fc_b
    const float* emb  = (const float*)d_in[2];     // row 0 used only
    const float* dWih = (const float*)d_in[7];
    const float* dWhh = (const float*)d_in[8];
    const float* dbih = (const float*)d_in[9];
    const float* dbhh = (const float*)d_in[10];
    const float* fcW  = (const float*)d_in[11];
    const float* fcb  = (const float*)d_in[12];
    float* out = (float*)d_out;

    // Scratch for folded weights: prefer d_ws; fall back to stashing in the
    // b=1 output region (overwritten later by bcast_out, after decode_seq
    // has consumed it).
    const size_t need = (size_t)(GK * HP + 2 * GK) * sizeof(float);
    float* scratch = (ws_size >= need) ? (float*)d_ws : (out + REGION);
    float* Wc = scratch;
    float* bc = Wc + GK * HP;
    float* g0 = bc + GK;

    fold_weights<<<GK, 128, 0, stream>>>(dWih, dWhh, dbih, dbhh, fcW, fcb, emb,
                                         Wc, bc, g0);
    decode_seq<<<1, 320, 0, stream>>>(Wc, bc, g0, out /* b=0 region */);
    bcast_out<<<127 * 8, 256, 0, stream>>>((const float4*)out, (float4*)out);
}

// Round 3
// 523.047 us; speedup vs baseline: 1.1025x; 1.1025x over previous
//
#include <hip/hip_runtime.h>

#define DH   66          // decoder hidden
#define GK   264         // 4*DH gate rows (torch order i,f,g,o)
#define HP   68          // row stride for folded weights
#define EMB  128
#define TSTEPS 512
#define REGION (TSTEPS*DH)   // 33792 floats per batch row

// ---------------------------------------------------------------------------
// readlane: VALU broadcast lane->SGPR (keeps the h ingest off the LDS pipe)
// ---------------------------------------------------------------------------
__device__ __forceinline__ float rl_f(float v, int lane) {
    return __uint_as_float((unsigned)__builtin_amdgcn_readlane((int)__float_as_uint(v), lane));
}

// quad broadcast via DPP quad_perm(K,K,K,K): every lane of a quad gets lane K's value
template<int K>
__device__ __forceinline__ float quad_bc(float v) {
    constexpr int ctrl = K | (K << 2) | (K << 4) | (K << 6);   // = K*0x55
    return __uint_as_float((unsigned)__builtin_amdgcn_update_dpp(
        0, (int)__float_as_uint(v), ctrl, 0xF, 0xF, true));
}

// ---------------------------------------------------------------------------
// Kernel 1: fold fc layer into recurrent weights (unchanged, verified exact).
// ---------------------------------------------------------------------------
__global__ void fold_weights(const float* __restrict__ Wih,   // [264][128]
                             const float* __restrict__ Whh,   // [264][66]
                             const float* __restrict__ bih,   // [264]
                             const float* __restrict__ bhh,   // [264]
                             const float* __restrict__ fcW,   // [128][66]
                             const float* __restrict__ fcb,   // [128]
                             const float* __restrict__ emb0,  // [128] row 0 of emb
                             float* __restrict__ Wc,          // [264][68]
                             float* __restrict__ bc,          // [264]
                             float* __restrict__ g0) {        // [264]
    __shared__ float a[EMB];
    const int k = blockIdx.x;
    const int j = threadIdx.x;
    if (j < EMB) a[j] = Wih[k * EMB + j];
    __syncthreads();
    if (j < DH) {
        float acc = Whh[k * DH + j];
        #pragma unroll 8
        for (int e = 0; e < EMB; ++e) acc = fmaf(a[e], fcW[e * DH + j], acc);
        Wc[k * HP + j] = acc;
    } else if (j == DH) {
        Wc[k * HP + DH] = 0.f;
        float acc = bih[k] + bhh[k];
        #pragma unroll 8
        for (int e = 0; e < EMB; ++e) acc = fmaf(a[e], fcb[e], acc);
        bc[k] = acc;
    } else if (j == DH + 1) {
        Wc[k * HP + DH + 1] = 0.f;
        float acc = bih[k] + bhh[k];
        #pragma unroll 8
        for (int e = 0; e < EMB; ++e) acc = fmaf(a[e], emb0[e], acc);
        g0[k] = acc;
    }
}

// ---------------------------------------------------------------------------
// Kernel 2: 512-step chain, quad-per-element layout.
//   lane = 4*q + gt : gate gt of element e = tid>>2 (e in 0..63)
//   elements 64,65 computed redundantly by all waves (wave parity picks which)
//   per step: NL+DPP combine (in-register) -> h to LDS -> 1 raw barrier ->
//             dot: 1 ds_read_b32/wave + 66 readlane + 132 fma
// ---------------------------------------------------------------------------
__global__ __launch_bounds__(256, 1)
void decode_seq(const float* __restrict__ Wc,
                const float* __restrict__ bc,
                const float* __restrict__ g0,
                float* __restrict__ hseq) {          // out region b=0: [512][66]
    __shared__ __align__(16) float h_s[2][HP];       // parity double buffer
    const int tid = threadIdx.x;
    const int gt  = tid & 3;          // gate: 0=i 1=f 2=g 3=o
    const int e   = tid >> 2;         // element 0..63
    const int w   = tid >> 6;         // wave id
    const int e2  = 64 + (w & 1);     // extra element (64 or 65), redundant
    const int r   = gt * DH + e;
    const int r2  = gt * DH + e2;

    // per-thread gate-row weights in registers (const-indexed -> no scratch)
    float wr[DH], wr2[DH];
    #pragma unroll
    for (int j = 0; j < DH; ++j) wr[j]  = Wc[r  * HP + j];
    #pragma unroll
    for (int j = 0; j < DH; ++j) wr2[j] = Wc[r2 * HP + j];
    const float bcm  = bc[r];
    const float bcm2 = bc[r2];
    float g  = g0[r];                 // step-0 gates (h0 = 0)
    float g2 = g0[r2];
    float c = 0.f, c2 = 0.f;

    // gate nonlinearity selectors: sigmoid for i,f,o; tanh for g (gt==2)
    const float sc = (gt == 2) ? 2.f : 1.f;
    const float m1 = (gt == 2) ? 2.f : 1.f;
    const float m0 = (gt == 2) ? -1.f : 0.f;

    const bool wmain = (gt == 0);                      // writer for own element
    const bool wextra = ((tid & 63) == 0) && (w < 2);  // tid0 -> h[64], tid64 -> h[65]

    #pragma unroll 2
    for (int step = 0; ; ++step) {
        const int b = step & 1;

        // ---- gate NL + quad combine (all lanes, no divergence) ----
        float ex = __expf(-sc * g);
        float a  = __fdividef(1.f, 1.f + ex);
        float v  = fmaf(a, m1, m0);                    // sig or tanh
        float iv = quad_bc<0>(v), fv = quad_bc<1>(v);
        float gv = quad_bc<2>(v), ov = quad_bc<3>(v);
        c = fmaf(fv, c, iv * gv);
        float ex2 = __expf(-2.f * c);
        float th  = fmaf(__fdividef(1.f, 1.f + ex2), 2.f, -1.f);
        float h = ov * th;

        // redundant extra element (same code, element e2)
        float ex_ = __expf(-sc * g2);
        float a_  = __fdividef(1.f, 1.f + ex_);
        float v_  = fmaf(a_, m1, m0);
        float iv_ = quad_bc<0>(v_), fv_ = quad_bc<1>(v_);
        float gv_ = quad_bc<2>(v_), ov_ = quad_bc<3>(v_);
        c2 = fmaf(fv_, c2, iv_ * gv_);
        float ex2_ = __expf(-2.f * c2);
        float th_  = fmaf(__fdividef(1.f, 1.f + ex2_), 2.f, -1.f);
        float h2 = ov_ * th_;

        if (wmain)  { h_s[b][e]  = h;  hseq[step * DH + e]  = h;  }
        if (wextra) { h_s[b][e2] = h2; hseq[step * DH + e2] = h2; }

        if (step == TSTEPS - 1) break;

        // raw barrier: drain LDS only — do NOT drain the global h stores
        asm volatile("s_waitcnt lgkmcnt(0)" ::: "memory");
        __builtin_amdgcn_s_barrier();
        asm volatile("" ::: "memory");

        // ---- dot: ingest h via 1 ds_read + readlane broadcasts ----
        const float hv0 = h_s[b][tid & 63];
        const float hv1 = h_s[b][64 + (tid & 1)];
        float acc = bcm, acc2 = bcm2;
        #pragma unroll
        for (int j = 0; j < 64; ++j) {
            const float hj = rl_f(hv0, j);
            acc  = fmaf(hj, wr[j],  acc);
            acc2 = fmaf(hj, wr2[j], acc2);
        }
        const float h64 = rl_f(hv1, 0);
        const float h65 = rl_f(hv1, 1);
        acc  = fmaf(h64, wr[64],  acc);   acc  = fmaf(h65, wr[65],  acc);
        acc2 = fmaf(h64, wr2[64], acc2);  acc2 = fmaf(h65, wr2[65], acc2);
        g = acc;  g2 = acc2;
    }
}

// ---------------------------------------------------------------------------
// Kernel 3: broadcast batch-0 region to b=1..127 (float4 copy, 17.2 MB write)
// ---------------------------------------------------------------------------
__global__ void bcast_out(const float4* src_base, float4* dst_base) {
    const int TILE = 1056;
    const float4* src = src_base + (blockIdx.x & 7) * TILE;
    float4* dst = dst_base + (size_t)(blockIdx.x + 8) * TILE;   // skip b=0 (8 tiles)
    #pragma unroll 2
    for (int i = threadIdx.x; i < TILE; i += 256) dst[i] = src[i];
}

// ---------------------------------------------------------------------------
extern "C" void kernel_launch(void* const* d_in, const int* in_sizes, int n_in,
                              void* d_out, int out_size, void* d_ws, size_t ws_size,
                              hipStream_t stream) {
    const float* emb  = (const float*)d_in[2];     // row 0 used only
    const float* dWih = (const float*)d_in[7];
    const float* dWhh = (const float*)d_in[8];
    const float* dbih = (const float*)d_in[9];
    const float* dbhh = (const float*)d_in[10];
    const float* fcW  = (const float*)d_in[11];
    const float* fcb  = (const float*)d_in[12];
    float* out = (float*)d_out;

    const size_t need = (size_t)(GK * HP + 2 * GK) * sizeof(float);
    float* scratch = (ws_size >= need) ? (float*)d_ws : (out + REGION);
    float* Wc = scratch;
    float* bc = Wc + GK * HP;
    float* g0 = bc + GK;

    fold_weights<<<GK, 128, 0, stream>>>(dWih, dWhh, dbih, dbhh, fcW, fcb, emb,
                                         Wc, bc, g0);
    decode_seq<<<1, 256, 0, stream>>>(Wc, bc, g0, out /* b=0 region */);
    bcast_out<<<127 * 8, 256, 0, stream>>>((const float4*)out, (float4*)out);
}

// Round 4
// 401.152 us; speedup vs baseline: 1.4375x; 1.3039x over previous
//
#include <hip/hip_runtime.h>

#define DH   66          // decoder hidden
#define GK   264         // 4*DH gate rows (torch order i,f,g,o)
#define HP   68          // row stride for folded weights
#define EMB  128
#define TSTEPS 512
#define REGION (TSTEPS*DH)   // 33792 floats per batch row

// readlane: VALU broadcast lane->SGPR (off the shared LDS pipe)
__device__ __forceinline__ float rl_f(float v, int lane) {
    return __uint_as_float((unsigned)__builtin_amdgcn_readlane((int)__float_as_uint(v), lane));
}

// quad broadcast via DPP quad_perm(K,K,K,K) — HW-verified in round 3 (absmax 0.0)
template<int K>
__device__ __forceinline__ float quad_bc(float v) {
    constexpr int ctrl = K * 0x55;
    return __uint_as_float((unsigned)__builtin_amdgcn_update_dpp(
        0, (int)__float_as_uint(v), ctrl, 0xF, 0xF, true));
}

// ---------------------------------------------------------------------------
// Kernel 1: fold fc layer into recurrent weights (unchanged, verified exact).
// ---------------------------------------------------------------------------
__global__ void fold_weights(const float* __restrict__ Wih,   // [264][128]
                             const float* __restrict__ Whh,   // [264][66]
                             const float* __restrict__ bih,   // [264]
                             const float* __restrict__ bhh,   // [264]
                             const float* __restrict__ fcW,   // [128][66]
                             const float* __restrict__ fcb,   // [128]
                             const float* __restrict__ emb0,  // [128] row 0 of emb
                             float* __restrict__ Wc,          // [264][68]
                             float* __restrict__ bc,          // [264]
                             float* __restrict__ g0) {        // [264]
    __shared__ float a[EMB];
    const int k = blockIdx.x;
    const int j = threadIdx.x;
    if (j < EMB) a[j] = Wih[k * EMB + j];
    __syncthreads();
    if (j < DH) {
        float acc = Whh[k * DH + j];
        #pragma unroll 8
        for (int e = 0; e < EMB; ++e) acc = fmaf(a[e], fcW[e * DH + j], acc);
        Wc[k * HP + j] = acc;
    } else if (j == DH) {
        Wc[k * HP + DH] = 0.f;
        float acc = bih[k] + bhh[k];
        #pragma unroll 8
        for (int e = 0; e < EMB; ++e) acc = fmaf(a[e], fcb[e], acc);
        bc[k] = acc;
    } else if (j == DH + 1) {
        Wc[k * HP + DH + 1] = 0.f;
        float acc = bih[k] + bhh[k];
        #pragma unroll 8
        for (int e = 0; e < EMB; ++e) acc = fmaf(a[e], emb0[e], acc);
        g0[k] = acc;
    }
}

// ---------------------------------------------------------------------------
// Kernel 2: 512-step chain. 320 threads = 5 waves, ONE gate-row per thread.
//   tid<256 : element e=tid>>2 (0..63), gate gt=tid&3
//   wave 4  : lanes 0-7 own e=64/65; lanes 8+ compute harmless duplicates
//   Weights: 17 NAMED float4 variables -> guaranteed VGPR residency.
//   Per step: NL + DPP quad combine -> h to LDS(parity dbuf) + global ->
//             raw lgkm-barrier -> 2 ds_read + 66 readlane + 66 fma (4 chains)
// ---------------------------------------------------------------------------
__global__ __launch_bounds__(320, 1)
void decode_seq(const float* __restrict__ Wc,
                const float* __restrict__ bc,
                const float* __restrict__ g0,
                float* __restrict__ hseq) {          // out region b=0: [512][66]
    __shared__ __align__(16) float h_s[2][HP];       // parity double buffer
    const int tid  = threadIdx.x;
    const int lane = tid & 63;
    const int gt   = tid & 3;          // 0=i 1=f 2=g 3=o
    int e; bool active;
    if (tid < 256) { e = tid >> 2; active = (gt == 0); }
    else { const int l = tid - 256; e = 64 + ((l >> 2) & 1); active = (gt == 0) && (l < 8); }
    const int r = gt * DH + e;

    // ---- weights: 17 named float4 = 68 VGPRs, no arrays, no indexing ----
    const float4* row4 = reinterpret_cast<const float4*>(Wc + r * HP);
    const float4 w0 = row4[0],  w1 = row4[1],  w2 = row4[2],  w3 = row4[3];
    const float4 w4 = row4[4],  w5 = row4[5],  w6 = row4[6],  w7 = row4[7];
    const float4 w8 = row4[8],  w9 = row4[9],  w10 = row4[10], w11 = row4[11];
    const float4 w12 = row4[12], w13 = row4[13], w14 = row4[14], w15 = row4[15];
    const float4 w16 = row4[16];
    const float bcm = bc[r];
    float g = g0[r];                   // step-0 gates (h0 = 0)
    float c = 0.f;

    // gate NL selectors: sigmoid for i,f,o; tanh(x)=2*sig(2x)-1 for g (gt==2)
    const float nsc = (gt == 2) ? -2.885390082f : -1.442695041f;  // -sc*log2(e)
    const float m1  = (gt == 2) ? 2.f : 1.f;
    const float m0  = (gt == 2) ? -1.f : 0.f;

    float* hp = hseq + e;              // per-writer output cursor

    #pragma unroll 2
    for (int step = 0; ; ++step) {
        const int b = step & 1;

        // ---- gate NL + quad combine (all in registers) ----
        const float t0 = __builtin_amdgcn_exp2f(nsc * g);
        const float av = __builtin_amdgcn_rcpf(1.f + t0);
        const float v  = fmaf(av, m1, m0);                 // sig or tanh
        const float iv = quad_bc<0>(v), fv = quad_bc<1>(v);
        const float gv = quad_bc<2>(v), ov = quad_bc<3>(v);
        c = fmaf(fv, c, iv * gv);
        const float t1 = __builtin_amdgcn_exp2f(-2.885390082f * c);
        const float th = fmaf(__builtin_amdgcn_rcpf(1.f + t1), 2.f, -1.f);
        const float h  = ov * th;

        if (active) { h_s[b][e] = h; *hp = h; }            // LDS + fire-and-forget
        hp += DH;

        if (step == TSTEPS - 1) break;

        // raw barrier: drain LDS only — never the global h stores
        asm volatile("s_waitcnt lgkmcnt(0)\n\ts_barrier" ::: "memory");

        // ---- dot: 2 ds_read + 66 readlane + 66 fma in 4 chains ----
        const float hv0 = h_s[b][lane];
        const float hv1 = h_s[b][64 + (lane & 1)];
        float a0 = bcm, a1 = 0.f, a2 = 0.f, a3 = 0.f;
        #define FMA4(i, W) \
            a0 = fmaf(rl_f(hv0, 4*(i)+0), W.x, a0); \
            a1 = fmaf(rl_f(hv0, 4*(i)+1), W.y, a1); \
            a2 = fmaf(rl_f(hv0, 4*(i)+2), W.z, a2); \
            a3 = fmaf(rl_f(hv0, 4*(i)+3), W.w, a3);
        FMA4(0,  w0)  FMA4(1,  w1)  FMA4(2,  w2)  FMA4(3,  w3)
        FMA4(4,  w4)  FMA4(5,  w5)  FMA4(6,  w6)  FMA4(7,  w7)
        FMA4(8,  w8)  FMA4(9,  w9)  FMA4(10, w10) FMA4(11, w11)
        FMA4(12, w12) FMA4(13, w13) FMA4(14, w14) FMA4(15, w15)
        #undef FMA4
        a0 = fmaf(rl_f(hv1, 0), w16.x, a0);
        a1 = fmaf(rl_f(hv1, 1), w16.y, a1);
        g = (a0 + a1) + (a2 + a3);
    }
}

// ---------------------------------------------------------------------------
// Kernel 3: broadcast batch-0 region to b=1..127 (float4 copy, 17.2 MB write)
// ---------------------------------------------------------------------------
__global__ void bcast_out(const float4* src_base, float4* dst_base) {
    const int TILE = 1056;
    const float4* src = src_base + (blockIdx.x & 7) * TILE;
    float4* dst = dst_base + (size_t)(blockIdx.x + 8) * TILE;   // skip b=0 (8 tiles)
    #pragma unroll 2
    for (int i = threadIdx.x; i < TILE; i += 256) dst[i] = src[i];
}

// ---------------------------------------------------------------------------
extern "C" void kernel_launch(void* const* d_in, const int* in_sizes, int n_in,
                              void* d_out, int out_size, void* d_ws, size_t ws_size,
                              hipStream_t stream) {
    const float* emb  = (const float*)d_in[2];     // row 0 used only
    const float* dWih = (const float*)d_in[7];
    const float* dWhh = (const float*)d_in[8];
    const float* dbih = (const float*)d_in[9];
    const float* dbhh = (const float*)d_in[10];
    const float* fcW  = (const float*)d_in[11];
    const float* fcb  = (const float*)d_in[12];
    float* out = (float*)d_out;

    const size_t need = (size_t)(GK * HP + 2 * GK) * sizeof(float);
    float* scratch = (ws_size >= need) ? (float*)d_ws : (out + REGION);
    float* Wc = scratch;
    float* bc = Wc + GK * HP;
    float* g0 = bc + GK;

    fold_weights<<<GK, 128, 0, stream>>>(dWih, dWhh, dbih, dbhh, fcW, fcb, emb,
                                         Wc, bc, g0);
    decode_seq<<<1, 320, 0, stream>>>(Wc, bc, g0, out /* b=0 region */);
    bcast_out<<<127 * 8, 256, 0, stream>>>((const float4*)out, (float4*)out);
}

// Round 6
// 380.058 us; speedup vs baseline: 1.5172x; 1.0555x over previous
//
#include <hip/hip_runtime.h>

#define DH   66          // decoder hidden
#define GK   264         // 4*DH gate rows (torch order i,f,g,o)
#define HP   68          // row stride for folded weights
#define EMB  128
#define TSTEPS 512
#define REGION (TSTEPS*DH)   // 33792 floats per batch row

// readlane: VALU broadcast lane->SGPR (off the shared LDS pipe)
__device__ __forceinline__ float rl_f(float v, int lane) {
    return __uint_as_float((unsigned)__builtin_amdgcn_readlane((int)__float_as_uint(v), lane));
}

// quad broadcast via DPP quad_perm(K,K,K,K) — HW-verified (absmax 0.0, r3/r4)
template<int K>
__device__ __forceinline__ float quad_bc(float v) {
    constexpr int ctrl = K * 0x55;
    return __uint_as_float((unsigned)__builtin_amdgcn_update_dpp(
        0, (int)__float_as_uint(v), ctrl, 0xF, 0xF, true));
}

// ---------------------------------------------------------------------------
// Kernel 1: fold fc layer into recurrent weights (unchanged, verified exact).
// ---------------------------------------------------------------------------
__global__ void fold_weights(const float* __restrict__ Wih,   // [264][128]
                             const float* __restrict__ Whh,   // [264][66]
                             const float* __restrict__ bih,   // [264]
                             const float* __restrict__ bhh,   // [264]
                             const float* __restrict__ fcW,   // [128][66]
                             const float* __restrict__ fcb,   // [128]
                             const float* __restrict__ emb0,  // [128] row 0 of emb
                             float* __restrict__ Wc,          // [264][68]
                             float* __restrict__ bc,          // [264]
                             float* __restrict__ g0) {        // [264]
    __shared__ float a[EMB];
    const int k = blockIdx.x;
    const int j = threadIdx.x;
    if (j < EMB) a[j] = Wih[k * EMB + j];
    __syncthreads();
    if (j < DH) {
        float acc = Whh[k * DH + j];
        #pragma unroll 8
        for (int e = 0; e < EMB; ++e) acc = fmaf(a[e], fcW[e * DH + j], acc);
        Wc[k * HP + j] = acc;
    } else if (j == DH) {
        Wc[k * HP + DH] = 0.f;
        float acc = bih[k] + bhh[k];
        #pragma unroll 8
        for (int e = 0; e < EMB; ++e) acc = fmaf(a[e], fcb[e], acc);
        bc[k] = acc;
    } else if (j == DH + 1) {
        Wc[k * HP + DH + 1] = 0.f;
        float acc = bih[k] + bhh[k];
        #pragma unroll 8
        for (int e = 0; e < EMB; ++e) acc = fmaf(a[e], emb0[e], acc);
        g0[k] = acc;
    }
}

// ---------------------------------------------------------------------------
// Kernel 2: 512-step chain. 256 threads = 4 waves = EXACTLY 1 wave per SIMD.
//   Main row:  lane quad q of element e=tid>>2, gate gt=tid&3 (e=0..63).
//   Extra row: EVERY quad also computes gates of e2 = 64 + (quad&1)
//              (redundant across quads -> zero divergence, perfect balance).
//   Per step: NL + DPP quad-combine (both rows) -> h to LDS(parity dbuf) +
//             global -> raw lgkm-only barrier ->
//             ingest: 2 ds_read + 66 readlane into UNIFORM hs[] (SGPRs) ->
//             dot: 132 v_fmac in 8 independent chains (SGPR x VGPR/AGPR).
// ---------------------------------------------------------------------------
__global__ __launch_bounds__(256, 1)
void decode_seq(const float* __restrict__ Wc,
                const float* __restrict__ bc,
                const float* __restrict__ g0,
                float* __restrict__ hseq) {          // out region b=0: [512][66]
    __shared__ __align__(16) float h_s[2][HP];       // parity double buffer
    const int tid  = threadIdx.x;
    const int lane = tid & 63;
    const int gt   = tid & 3;              // 0=i 1=f 2=g 3=o
    const int e    = tid >> 2;             // 0..63
    const int e2   = 64 + ((tid >> 2) & 1);// 64/65, alternating per quad
    const int r    = gt * DH + e;
    const int r2   = gt * DH + e2;

    // ---- weights: 34 named float4 (no arrays, no indexing) ----
    const float4* rowA = reinterpret_cast<const float4*>(Wc + r  * HP);
    const float4* rowB = reinterpret_cast<const float4*>(Wc + r2 * HP);
    const float4 wa0 = rowA[0],  wa1 = rowA[1],  wa2 = rowA[2],  wa3 = rowA[3];
    const float4 wa4 = rowA[4],  wa5 = rowA[5],  wa6 = rowA[6],  wa7 = rowA[7];
    const float4 wa8 = rowA[8],  wa9 = rowA[9],  wa10 = rowA[10], wa11 = rowA[11];
    const float4 wa12 = rowA[12], wa13 = rowA[13], wa14 = rowA[14], wa15 = rowA[15];
    const float4 wa16 = rowA[16];
    const float4 wb0 = rowB[0],  wb1 = rowB[1],  wb2 = rowB[2],  wb3 = rowB[3];
    const float4 wb4 = rowB[4],  wb5 = rowB[5],  wb6 = rowB[6],  wb7 = rowB[7];
    const float4 wb8 = rowB[8],  wb9 = rowB[9],  wb10 = rowB[10], wb11 = rowB[11];
    const float4 wb12 = rowB[12], wb13 = rowB[13], wb14 = rowB[14], wb15 = rowB[15];
    const float4 wb16 = rowB[16];
    const float bcA = bc[r], bcB = bc[r2];
    float g  = g0[r],  g2 = g0[r2];        // step-0 gates (h0 = 0)
    float c  = 0.f,    c2 = 0.f;

    // gate NL selectors: sigmoid for i,f,o; tanh(x)=2*sig(2x)-1 for g (gt==2)
    const float nsc = (gt == 2) ? -2.885390082f : -1.442695041f;  // -sc*log2(e)
    const float m1  = (gt == 2) ? 2.f : 1.f;
    const float m0  = (gt == 2) ? -1.f : 0.f;

    const bool wA = (gt == 0);                    // 64 main writers
    const bool wB = (tid == 0) | (tid == 4);      // tid0 -> h[64], tid4 -> h[65]
    float* hpA = hseq + e;
    float* hpB = hseq + e2;

    #pragma unroll 2
    for (int step = 0; ; ++step) {
        const int b = step & 1;

        // ---- cell update, main row ----
        const float t0 = __builtin_amdgcn_exp2f(nsc * g);
        const float v  = fmaf(__builtin_amdgcn_rcpf(1.f + t0), m1, m0);
        const float iv = quad_bc<0>(v), fv = quad_bc<1>(v);
        const float gv = quad_bc<2>(v), ov = quad_bc<3>(v);
        c = fmaf(fv, c, iv * gv);
        const float t1 = __builtin_amdgcn_exp2f(-2.885390082f * c);
        const float h  = ov * fmaf(__builtin_amdgcn_rcpf(1.f + t1), 2.f, -1.f);

        // ---- cell update, extra row (e2), identical structure ----
        const float u0 = __builtin_amdgcn_exp2f(nsc * g2);
        const float v2 = fmaf(__builtin_amdgcn_rcpf(1.f + u0), m1, m0);
        const float iv2 = quad_bc<0>(v2), fv2 = quad_bc<1>(v2);
        const float gv2 = quad_bc<2>(v2), ov2 = quad_bc<3>(v2);
        c2 = fmaf(fv2, c2, iv2 * gv2);
        const float u1 = __builtin_amdgcn_exp2f(-2.885390082f * c2);
        const float h2 = ov2 * fmaf(__builtin_amdgcn_rcpf(1.f + u1), 2.f, -1.f);

        if (wA) { h_s[b][e]  = h;  *hpA = h;  }   // LDS + fire-and-forget global
        if (wB) { h_s[b][e2] = h2; *hpB = h2; }
        hpA += DH; hpB += DH;

        if (step == TSTEPS - 1) break;

        // raw barrier: drain LDS only — never the global h stores
        asm volatile("s_waitcnt lgkmcnt(0)\n\ts_barrier" ::: "memory");

        // ---- ingest phase: 2 ds_read + 66 readlane -> uniform hs[] ----
        const float hv0 = h_s[b][lane];
        const float hv1 = h_s[b][64 + (lane & 1)];
        float hs[66];
        #pragma unroll
        for (int j = 0; j < 64; ++j) hs[j] = rl_f(hv0, j);
        hs[64] = rl_f(hv1, 0);
        hs[65] = rl_f(hv1, 1);

        // ---- dot phase: 132 fma, 8 independent chains ----
        float x0 = bcA, x1 = 0.f, x2 = 0.f, x3 = 0.f;
        float y0 = bcB, y1 = 0.f, y2 = 0.f, y3 = 0.f;
        #define FMA8(i, WA, WB) \
            x0 = fmaf(hs[4*(i)+0], WA.x, x0);  y0 = fmaf(hs[4*(i)+0], WB.x, y0); \
            x1 = fmaf(hs[4*(i)+1], WA.y, x1);  y1 = fmaf(hs[4*(i)+1], WB.y, y1); \
            x2 = fmaf(hs[4*(i)+2], WA.z, x2);  y2 = fmaf(hs[4*(i)+2], WB.z, y2); \
            x3 = fmaf(hs[4*(i)+3], WA.w, x3);  y3 = fmaf(hs[4*(i)+3], WB.w, y3);
        FMA8(0,  wa0,  wb0)  FMA8(1,  wa1,  wb1)  FMA8(2,  wa2,  wb2)
        FMA8(3,  wa3,  wb3)  FMA8(4,  wa4,  wb4)  FMA8(5,  wa5,  wb5)
        FMA8(6,  wa6,  wb6)  FMA8(7,  wa7,  wb7)  FMA8(8,  wa8,  wb8)
        FMA8(9,  wa9,  wb9)  FMA8(10, wa10, wb10) FMA8(11, wa11, wb11)
        FMA8(12, wa12, wb12) FMA8(13, wa13, wb13) FMA8(14, wa14, wb14)
        FMA8(15, wa15, wb15)
        #undef FMA8
        x0 = fmaf(hs[64], wa16.x, x0);  y0 = fmaf(hs[64], wb16.x, y0);
        x1 = fmaf(hs[65], wa16.y, x1);  y1 = fmaf(hs[65], wb16.y, y1);
        g  = (x0 + x1) + (x2 + x3);
        g2 = (y0 + y1) + (y2 + y3);
    }
}

// ---------------------------------------------------------------------------
// Kernel 3: broadcast batch-0 region to b=1..127 (float4 copy, 17.2 MB write)
// ---------------------------------------------------------------------------
__global__ void bcast_out(const float4* src_base, float4* dst_base) {
    const int TILE = 1056;
    const float4* src = src_base + (blockIdx.x & 7) * TILE;
    float4* dst = dst_base + (size_t)(blockIdx.x + 8) * TILE;   // skip b=0 (8 tiles)
    #pragma unroll 2
    for (int i = threadIdx.x; i < TILE; i += 256) dst[i] = src[i];
}

// ---------------------------------------------------------------------------
extern "C" void kernel_launch(void* const* d_in, const int* in_sizes, int n_in,
                              void* d_out, int out_size, void* d_ws, size_t ws_size,
                              hipStream_t stream) {
    const float* emb  = (const float*)d_in[2];     // row 0 used only
    const float* dWih = (const float*)d_in[7];
    const float* dWhh = (const float*)d_in[8];
    const float* dbih = (const float*)d_in[9];
    const float* dbhh = (const float*)d_in[10];
    const float* fcW  = (const float*)d_in[11];
    const float* fcb  = (const float*)d_in[12];
    float* out = (float*)d_out;

    const size_t need = (size_t)(GK * HP + 2 * GK) * sizeof(float);
    float* scratch = (ws_size >= need) ? (float*)d_ws : (out + REGION);
    float* Wc = scratch;
    float* bc = Wc + GK * HP;
    float* g0 = bc + GK;

    fold_weights<<<GK, 128, 0, stream>>>(dWih, dWhh, dbih, dbhh, fcW, fcb, emb,
                                         Wc, bc, g0);
    decode_seq<<<1, 256, 0, stream>>>(Wc, bc, g0, out /* b=0 region */);
    bcast_out<<<127 * 8, 256, 0, stream>>>((const float4*)out, (float4*)out);
}

// Round 9
// 371.454 us; speedup vs baseline: 1.5524x; 1.0232x over previous
//
#include <hip/hip_runtime.h>

#define DH   66          // decoder hidden
#define GK   264         // 4*DH gate rows (torch order i,f,g,o)
#define EMB  128
#define TSTEPS 512
#define REGION (TSTEPS*DH)   // 33792 floats per batch row

// scratch layout (floats): Wt[256*68] | We[8*68] | bmain[256] | bext[8] | g0p[256] | g0e[8]
#define WT_SZ (256*68)
#define WE_SZ (8*68)

template<int C>
__device__ __forceinline__ float dpp_f(float v) {
    return __uint_as_float((unsigned)__builtin_amdgcn_update_dpp(
        0, (int)__float_as_uint(v), C, 0xF, 0xF, true));
}
// quad butterfly sum: all 4 lanes of each quad get the quad's total
__device__ __forceinline__ float qsum(float v) {
    v += dpp_f<0xB1>(v);   // quad_perm [1,0,3,2]  (xor 1)
    v += dpp_f<0x4E>(v);   // quad_perm [2,3,0,1]  (xor 2)
    return v;
}
__device__ __forceinline__ float sig_(float x) {
    return __builtin_amdgcn_rcpf(1.f + __builtin_amdgcn_exp2f(-1.442695041f * x));
}
__device__ __forceinline__ float th_(float x) {
    return fmaf(__builtin_amdgcn_rcpf(1.f + __builtin_amdgcn_exp2f(-2.885390082f * x)), 2.f, -1.f);
}

// ---------------------------------------------------------------------------
// Kernel 1: fold fc into recurrence + pack for the quad-sliced decode layout.
//   row r = gate*66+e of W_comb = dec_W_ih@fc_W + dec_W_hh (j<66; j>=66 -> 0)
//   Wt[((e*4+(j&3))*17 + (j>>2))*4 + gate]  (e<64)   — lane-contig [k][gate]
//   We[(((e-64)*4+(j&3))*17 + (j>>2))*4 + gate] (e>=64)
//   bmain/bext: bias packed [e][gate]; g0p/g0e: step-0 gates packed [e][gate]
// ---------------------------------------------------------------------------
__global__ void fold_weights(const float* __restrict__ Wih,   // [264][128]
                             const float* __restrict__ Whh,   // [264][66]
                             const float* __restrict__ bih,   // [264]
                             const float* __restrict__ bhh,   // [264]
                             const float* __restrict__ fcW,   // [128][66]
                             const float* __restrict__ fcb,   // [128]
                             const float* __restrict__ emb0,  // [128]
                             float* __restrict__ Wt, float* __restrict__ We,
                             float* __restrict__ bmain, float* __restrict__ bext,
                             float* __restrict__ g0p, float* __restrict__ g0e) {
    __shared__ float a[EMB];
    const int r = blockIdx.x;
    const int j = threadIdx.x;
    if (j < EMB) a[j] = Wih[r * EMB + j];
    __syncthreads();
    const int gate = r / DH;
    const int e    = r - gate * DH;
    if (j < 68) {
        float val = 0.f;
        if (j < DH) {
            float acc = Whh[r * DH + j];
            #pragma unroll 8
            for (int t = 0; t < EMB; ++t) acc = fmaf(a[t], fcW[t * DH + j], acc);
            val = acc;
        }
        if (e < 64) Wt[((e * 4 + (j & 3)) * 17 + (j >> 2)) * 4 + gate] = val;
        else        We[(((e - 64) * 4 + (j & 3)) * 17 + (j >> 2)) * 4 + gate] = val;
    } else if (j == 68) {
        float acc = bih[r] + bhh[r];
        #pragma unroll 8
        for (int t = 0; t < EMB; ++t) acc = fmaf(a[t], fcb[t], acc);
        if (e < 64) bmain[e * 4 + gate] = acc; else bext[(e - 64) * 4 + gate] = acc;
    } else if (j == 69) {
        float acc = bih[r] + bhh[r];
        #pragma unroll 8
        for (int t = 0; t < EMB; ++t) acc = fmaf(a[t], emb0[t], acc);
        if (e < 64) g0p[e * 4 + gate] = acc; else g0e[(e - 64) * 4 + gate] = acc;
    }
}

// ---------------------------------------------------------------------------
// Kernel 2: 512-step chain. 256 threads = 4 waves = 1 wave/SIMD. NO readlane.
//   quad q = element e (0..63); lane gt of quad owns j-slice {gt, gt+4, ...}.
//   Per k: 1 h scalar x float4 weights -> 4 gate accumulators (all 4 gates of e).
//   Quad butterfly (2 DPP stages) -> every lane holds all 4 gates.
//   BIAS IS ADDED AFTER THE BUTTERFLY (was summed 4x in round 7 — the bug).
//   Extra elements 64/65: same j-sliced scheme per quad parity (uniform).
//   h exchanged via transposed LDS hT[buf][j&3][j>>2] (bank-disjoint rows):
//   ingest = 4 ds_read_b128 + 1 ds_read_b32 per lane. One lgkm-only barrier.
// ---------------------------------------------------------------------------
__global__ __launch_bounds__(256, 1)
void decode_seq(const float* __restrict__ Wt, const float* __restrict__ We,
                const float* __restrict__ bmain, const float* __restrict__ bext,
                const float* __restrict__ g0p, const float* __restrict__ g0e,
                float* __restrict__ hseq) {          // out region b=0: [512][66]
    __shared__ __align__(16) float hT[2][4][20];     // [buf][row=j&3][col=j>>2]
    const int tid = threadIdx.x;
    const int gt  = tid & 3;
    const int q   = tid >> 2;          // element e = q
    const int par = q & 1;             // extra element e2 = 64 + par

    // ---- weights: 17 + 17 named float4 (lane-contiguous, [k][gate]) ----
    const float4* wp = reinterpret_cast<const float4*>(Wt + tid * 68);
    const float4 m0 = wp[0],  m1 = wp[1],  m2 = wp[2],  m3 = wp[3];
    const float4 m4 = wp[4],  m5 = wp[5],  m6 = wp[6],  m7 = wp[7];
    const float4 m8 = wp[8],  m9 = wp[9],  m10 = wp[10], m11 = wp[11];
    const float4 m12 = wp[12], m13 = wp[13], m14 = wp[14], m15 = wp[15];
    const float4 m16 = wp[16];
    const float4* xp = reinterpret_cast<const float4*>(We + (par * 4 + gt) * 68);
    const float4 x0 = xp[0],  x1 = xp[1],  x2 = xp[2],  x3 = xp[3];
    const float4 x4 = xp[4],  x5 = xp[5],  x6 = xp[6],  x7 = xp[7];
    const float4 x8 = xp[8],  x9 = xp[9],  x10 = xp[10], x11 = xp[11];
    const float4 x12 = xp[12], x13 = xp[13], x14 = xp[14], x15 = xp[15];
    const float4 x16 = xp[16];
    const float4 bm = reinterpret_cast<const float4*>(bmain)[q];
    const float4 be = reinterpret_cast<const float4*>(bext)[par];
    float4 ga = reinterpret_cast<const float4*>(g0p)[q];    // current gates (i,f,g,o) of e
    float4 gb = reinterpret_cast<const float4*>(g0e)[par];  // current gates of e2
    float c = 0.f, c2 = 0.f;

    // zero the pad slots read by rows 2,3 at col 16 (j=66,67)
    if (tid < 4) hT[tid & 1][2 + (tid >> 1)][16] = 0.f;

    const bool wA  = (gt == 0);                  // writer for element q
    const bool wE  = (tid == 0) | (tid == 4);    // tid0 -> e64, tid4 -> e65
    float* hpA = hseq + q;
    float* hpE = hseq + 64 + par;

    #pragma unroll 2
    for (int step = 0; ; ++step) {
        const int b = step & 1;

        // ---- full in-lane cell update (gates already complete per lane) ----
        const float iv = sig_(ga.x), fv = sig_(ga.y), gv = th_(ga.z), ov = sig_(ga.w);
        c = fmaf(fv, c, iv * gv);
        const float h = ov * th_(c);
        const float i2 = sig_(gb.x), f2 = sig_(gb.y), g2 = th_(gb.z), o2 = sig_(gb.w);
        c2 = fmaf(f2, c2, i2 * g2);
        const float h2 = o2 * th_(c2);

        if (wA) { hT[b][q & 3][q >> 2] = h;  *hpA = h;  }
        if (wE) { hT[b][par][16]       = h2; *hpE = h2; }
        hpA += DH; hpE += DH;

        if (step == TSTEPS - 1) break;

        // raw barrier: drain LDS only — never the global h stores
        asm volatile("s_waitcnt lgkmcnt(0)\n\ts_barrier" ::: "memory");

        // ---- ingest own j-slice: 4 b128 + 1 b32, bank-disjoint rows ----
        const float4* hr = reinterpret_cast<const float4*>(&hT[b][gt][0]);
        const float4 p0 = hr[0], p1 = hr[1], p2 = hr[2], p3 = hr[3];
        const float  px = hT[b][gt][16];

        // ---- dot: per k, 1 h scalar x (main f4 + extra f4) = 8 fma ----
        // accumulators start at ZERO; bias added once after the butterfly
        float ai = 0.f, af = 0.f, ag = 0.f, ao = 0.f;
        float bi = 0.f, bf = 0.f, bg = 0.f, bo = 0.f;
        #define KSTEP(HK, WM, WX) \
            ai = fmaf(HK, WM.x, ai); af = fmaf(HK, WM.y, af); \
            ag = fmaf(HK, WM.z, ag); ao = fmaf(HK, WM.w, ao); \
            bi = fmaf(HK, WX.x, bi); bf = fmaf(HK, WX.y, bf); \
            bg = fmaf(HK, WX.z, bg); bo = fmaf(HK, WX.w, bo);
        KSTEP(p0.x, m0,  x0)  KSTEP(p0.y, m1,  x1)
        KSTEP(p0.z, m2,  x2)  KSTEP(p0.w, m3,  x3)
        KSTEP(p1.x, m4,  x4)  KSTEP(p1.y, m5,  x5)
        KSTEP(p1.z, m6,  x6)  KSTEP(p1.w, m7,  x7)
        KSTEP(p2.x, m8,  x8)  KSTEP(p2.y, m9,  x9)
        KSTEP(p2.z, m10, x10) KSTEP(p2.w, m11, x11)
        KSTEP(p3.x, m12, x12) KSTEP(p3.y, m13, x13)
        KSTEP(p3.z, m14, x14) KSTEP(p3.w, m15, x15)
        KSTEP(px,   m16, x16)
        #undef KSTEP

        // ---- quad butterflies + bias-once: complete 4 gates in every lane ----
        ga = make_float4(bm.x + qsum(ai), bm.y + qsum(af),
                         bm.z + qsum(ag), bm.w + qsum(ao));
        gb = make_float4(be.x + qsum(bi), be.y + qsum(bf),
                         be.z + qsum(bg), be.w + qsum(bo));
    }
}

// ---------------------------------------------------------------------------
// Kernel 3: broadcast batch-0 region to b=1..127 (float4 copy, 17.2 MB write)
// ---------------------------------------------------------------------------
__global__ void bcast_out(const float4* src_base, float4* dst_base) {
    const int TILE = 1056;
    const float4* src = src_base + (blockIdx.x & 7) * TILE;
    float4* dst = dst_base + (size_t)(blockIdx.x + 8) * TILE;   // skip b=0 (8 tiles)
    #pragma unroll 2
    for (int i = threadIdx.x; i < TILE; i += 256) dst[i] = src[i];
}

// ---------------------------------------------------------------------------
extern "C" void kernel_launch(void* const* d_in, const int* in_sizes, int n_in,
                              void* d_out, int out_size, void* d_ws, size_t ws_size,
                              hipStream_t stream) {
    const float* emb  = (const float*)d_in[2];     // row 0 used only
    const float* dWih = (const float*)d_in[7];
    const float* dWhh = (const float*)d_in[8];
    const float* dbih = (const float*)d_in[9];
    const float* dbhh = (const float*)d_in[10];
    const float* fcW  = (const float*)d_in[11];
    const float* fcb  = (const float*)d_in[12];
    float* out = (float*)d_out;

    const size_t need = (size_t)(WT_SZ + WE_SZ + 256 + 8 + 256 + 8) * sizeof(float);
    float* scratch = (ws_size >= need) ? (float*)d_ws : (out + REGION);
    float* Wt    = scratch;
    float* We    = Wt + WT_SZ;
    float* bmain = We + WE_SZ;
    float* bext  = bmain + 256;
    float* g0p   = bext + 8;
    float* g0e   = g0p + 256;

    fold_weights<<<GK, 128, 0, stream>>>(dWih, dWhh, dbih, dbhh, fcW, fcb, emb,
                                         Wt, We, bmain, bext, g0p, g0e);
    decode_seq<<<1, 256, 0, stream>>>(Wt, We, bmain, bext, g0p, g0e,
                                      out /* b=0 region */);
    bcast_out<<<127 * 8, 256, 0, stream>>>((const float4*)out, (float4*)out);
}

// Round 10
// 318.316 us; speedup vs baseline: 1.8115x; 1.1669x over previous
//
#include <hip/hip_runtime.h>

#define DH   66          // decoder hidden
#define GK   264         // 4*DH gate rows (torch order i,f,g,o)
#define EMB  128
#define TSTEPS 512
#define REGION (TSTEPS*DH)   // 33792 floats per batch row

// scratch (floats): Wt[17408] | Wex[640] | bmain[256] | bext[8] | g0p[256] | g0e[8]
#define WT_SZ (256*68)
#define WEX_SZ (32*20)

#define L2E  1.442695041f
#define L2E2 2.885390082f

template<int C>
__device__ __forceinline__ float dpp_f(float v) {
    return __uint_as_float((unsigned)__builtin_amdgcn_update_dpp(
        0, (int)__float_as_uint(v), C, 0xF, 0xF, true));
}
// quad all-reduce sum (verified r9)
__device__ __forceinline__ float qsum(float v) {
    v += dpp_f<0xB1>(v);   // quad_perm [1,0,3,2] (xor 1)
    v += dpp_f<0x4E>(v);   // quad_perm [2,3,0,1] (xor 2)
    return v;
}
// quad broadcast (verified r3/r4)
template<int K>
__device__ __forceinline__ float quad_bc(float v) {
    return __uint_as_float((unsigned)__builtin_amdgcn_update_dpp(
        0, (int)__float_as_uint(v), K * 0x55, 0xF, 0xF, true));
}
// tanh for c (true units): 2*sig(2c)-1 via exp2
__device__ __forceinline__ float th_c(float x) {
    return fmaf(__builtin_amdgcn_rcpf(1.f + __builtin_amdgcn_exp2f(-L2E2 * x)), 2.f, -1.f);
}

// ---------------------------------------------------------------------------
// Kernel 1: fold fc into recurrence; pack quad-sliced layout; prescale by
// log2e (rows of gate g by 2*log2e) so decode NL is bare exp2.
//   main: Wt[((e*4+(j&3))*17 + (j>>2))*4 + gate]  (e<64)
//   extra rows (e=64,65): qq = gate*2+(e-64); Wex[((qq*4+(j&3))*20 + (j>>2))]
//   bmain/g0p packed [e*4+gate]; bext/g0e packed [(e-64)*4+gate]
// ---------------------------------------------------------------------------
__global__ void fold_weights(const float* __restrict__ Wih,   // [264][128]
                             const float* __restrict__ Whh,   // [264][66]
                             const float* __restrict__ bih,   // [264]
                             const float* __restrict__ bhh,   // [264]
                             const float* __restrict__ fcW,   // [128][66]
                             const float* __restrict__ fcb,   // [128]
                             const float* __restrict__ emb0,  // [128]
                             float* __restrict__ Wt, float* __restrict__ Wex,
                             float* __restrict__ bmain, float* __restrict__ bext,
                             float* __restrict__ g0p, float* __restrict__ g0e) {
    __shared__ float a[EMB];
    const int r = blockIdx.x;
    const int j = threadIdx.x;
    if (j < EMB) a[j] = Wih[r * EMB + j];
    __syncthreads();
    const int gate = r / DH;
    const int e    = r - gate * DH;
    const float s  = (gate == 2) ? L2E2 : L2E;     // prescale
    if (j < 68) {
        float val = 0.f;
        if (j < DH) {
            float acc = Whh[r * DH + j];
            #pragma unroll 8
            for (int t = 0; t < EMB; ++t) acc = fmaf(a[t], fcW[t * DH + j], acc);
            val = acc * s;
        }
        if (e < 64) Wt[((e * 4 + (j & 3)) * 17 + (j >> 2)) * 4 + gate] = val;
        else {
            const int qq = gate * 2 + (e - 64);
            Wex[(qq * 4 + (j & 3)) * 20 + (j >> 2)] = val;
        }
    } else if (j == 68) {
        float acc = bih[r] + bhh[r];
        #pragma unroll 8
        for (int t = 0; t < EMB; ++t) acc = fmaf(a[t], fcb[t], acc);
        acc *= s;
        if (e < 64) bmain[e * 4 + gate] = acc; else bext[(e - 64) * 4 + gate] = acc;
    } else if (j == 69) {
        float acc = bih[r] + bhh[r];
        #pragma unroll 8
        for (int t = 0; t < EMB; ++t) acc = fmaf(a[t], emb0[t], acc);
        acc *= s;
        if (e < 64) g0p[e * 4 + gate] = acc; else g0e[(e - 64) * 4 + gate] = acc;
    }
}

// ---------------------------------------------------------------------------
// Kernel 2: 512-step chain. 256 threads = 4 waves = 1 wave/SIMD.
//   Main: quad q = element; lane gt owns j-slice {gt,gt+4,...}; 17 KSTEP x4 fma;
//   reduce-scatter (2 DPP stages + cndmask) -> lane gt holds gate-gt total;
//   +bias once; NL per-lane (2 trans); quad_bc recombine; in-lane c,h.
//   Extra (e=64,65): every quad-group computes rows qq=(lane>>2)&7 once
//   (+17 fma on the SAME p-regs), qsum, +bias, ds_bpermute scatters the 8
//   row totals gate-per-lane; same NL/quad_bc/cell path. Zero divergence.
//   h via transposed LDS hT[buf][j&3][j>>2]; one lgkm-only barrier/step.
// ---------------------------------------------------------------------------
__global__ __launch_bounds__(256, 1)
void decode_seq(const float* __restrict__ Wt, const float* __restrict__ Wex,
                const float* __restrict__ bmain, const float* __restrict__ bext,
                const float* __restrict__ g0p, const float* __restrict__ g0e,
                float* __restrict__ hseq) {          // out region b=0: [512][66]
    __shared__ __align__(16) float hT[2][4][20];     // [buf][row=j&3][col=j>>2]
    const int tid  = threadIdx.x;
    const int lane = tid & 63;
    const int gt   = tid & 3;
    const int q    = tid >> 2;             // main element (0..63)
    const int parX = (lane >> 2) & 1;      // consumed extra element 64+parX
    const int qqP  = (lane >> 2) & 7;      // produced extra row index

    // ---- main weights: 17 named float4 ----
    const float4* wp = reinterpret_cast<const float4*>(Wt + tid * 68);
    const float4 m0 = wp[0],  m1 = wp[1],  m2 = wp[2],  m3 = wp[3];
    const float4 m4 = wp[4],  m5 = wp[5],  m6 = wp[6],  m7 = wp[7];
    const float4 m8 = wp[8],  m9 = wp[9],  m10 = wp[10], m11 = wp[11];
    const float4 m12 = wp[12], m13 = wp[13], m14 = wp[14], m15 = wp[15];
    const float4 m16 = wp[16];
    // ---- extra-row weights: 17 scalars (4 f4 + 1), 80B-aligned rows ----
    const float* xbase = Wex + (qqP * 4 + gt) * 20;
    const float4 xv0 = reinterpret_cast<const float4*>(xbase)[0];
    const float4 xv1 = reinterpret_cast<const float4*>(xbase)[1];
    const float4 xv2 = reinterpret_cast<const float4*>(xbase)[2];
    const float4 xv3 = reinterpret_cast<const float4*>(xbase)[3];
    const float  xv4 = xbase[16];

    const float bsel = bmain[tid];                       // gate-gt bias of elem q
    const float bx   = bext[(qqP & 1) * 4 + (qqP >> 1)]; // bias of produced row
    float g   = g0p[tid];                                // step-0 gate (prescaled)
    float gbx = g0e[parX * 4 + gt];                      // step-0 extra gate
    float c = 0.f, c2 = 0.f;

    // NL selectors: sigmoid for i,f,o; tanh(x)=2*sig-1 for g (gt==2)
    const float m1c = (gt == 2) ? 2.f : 1.f;
    const float m0c = (gt == 2) ? -1.f : 0.f;
    // bpermute source: gate (lane&3) of element 64+parX lives in quad
    // src_qq = (lane&3)*2 + parX -> lane src_qq*4 ; byte addr = src*4
    const int bpaddr = (((gt << 1) | parX) << 2) << 2;

    // zero pad slots read by rows 2,3 at col 16 (j=66,67)
    if (tid < 4) hT[tid & 1][2 + (tid >> 1)][16] = 0.f;

    const bool wA = (gt == 0);                  // writer for element q
    const bool wE = (tid == 0) | (tid == 4);    // tid0 -> e64, tid4 -> e65
    float* hpA = hseq + q;
    float* hpE = hseq + 64 + parX;

    #pragma unroll 2
    for (int step = 0; ; ++step) {
        const int b = step & 1;

        // ---- main cell: per-lane NL -> quad_bc -> c,h ----
        const float v  = fmaf(__builtin_amdgcn_rcpf(1.f + __builtin_amdgcn_exp2f(-g)), m1c, m0c);
        const float iv = quad_bc<0>(v), fv = quad_bc<1>(v);
        const float gv = quad_bc<2>(v), ov = quad_bc<3>(v);
        c = fmaf(fv, c, iv * gv);
        const float h = ov * th_c(c);

        // ---- extra cell (same pattern; quads track e64/e65 by parX) ----
        const float vx  = fmaf(__builtin_amdgcn_rcpf(1.f + __builtin_amdgcn_exp2f(-gbx)), m1c, m0c);
        const float iv2 = quad_bc<0>(vx), fv2 = quad_bc<1>(vx);
        const float gv2 = quad_bc<2>(vx), ov2 = quad_bc<3>(vx);
        c2 = fmaf(fv2, c2, iv2 * gv2);
        const float h2 = ov2 * th_c(c2);

        if (wA) { hT[b][q & 3][q >> 2] = h;  *hpA = h;  }
        if (wE) { hT[b][parX][16]      = h2; *hpE = h2; }
        hpA += DH; hpE += DH;

        if (step == TSTEPS - 1) break;

        // raw barrier: drain LDS only — never the global h stores
        asm volatile("s_waitcnt lgkmcnt(0)\n\ts_barrier" ::: "memory");

        // ---- ingest own j-slice: 4 b128 + 1 b32 (bank-disjoint rows) ----
        const float4* hr = reinterpret_cast<const float4*>(&hT[b][gt][0]);
        const float4 p0 = hr[0], p1 = hr[1], p2 = hr[2], p3 = hr[3];
        const float  px = hT[b][gt][16];

        // ---- main dot: 68 fma (4 chains) + extra dot: 17 fma (1 chain) ----
        float ai = 0.f, af = 0.f, ag = 0.f, ao = 0.f, ax = 0.f;
        #define KSTEP(HK, WM, WX) \
            ai = fmaf(HK, WM.x, ai); af = fmaf(HK, WM.y, af); \
            ag = fmaf(HK, WM.z, ag); ao = fmaf(HK, WM.w, ao); \
            ax = fmaf(HK, WX, ax);
        KSTEP(p0.x, m0,  xv0.x)  KSTEP(p0.y, m1,  xv0.y)
        KSTEP(p0.z, m2,  xv0.z)  KSTEP(p0.w, m3,  xv0.w)
        KSTEP(p1.x, m4,  xv1.x)  KSTEP(p1.y, m5,  xv1.y)
        KSTEP(p1.z, m6,  xv1.z)  KSTEP(p1.w, m7,  xv1.w)
        KSTEP(p2.x, m8,  xv2.x)  KSTEP(p2.y, m9,  xv2.y)
        KSTEP(p2.z, m10, xv2.z)  KSTEP(p2.w, m11, xv2.w)
        KSTEP(p3.x, m12, xv3.x)  KSTEP(p3.y, m13, xv3.y)
        KSTEP(p3.z, m14, xv3.z)  KSTEP(p3.w, m15, xv3.w)
        KSTEP(px,   m16, xv4)
        #undef KSTEP

        // ---- main reduce-scatter: lane gt ends with gate-gt total ----
        const bool s1 = (gt & 1), s2h = (gt & 2);
        float keepA = s1 ? af : ai, sendA = s1 ? ai : af;
        float keepB = s1 ? ao : ag, sendB = s1 ? ag : ao;
        const float x1 = keepA + dpp_f<0xB1>(sendA);
        const float x2 = keepB + dpp_f<0xB1>(sendB);
        float keep2 = s2h ? x2 : x1, send2 = s2h ? x1 : x2;
        g = bsel + keep2 + dpp_f<0x4E>(send2);

        // ---- extra: quad all-reduce + bias, then gate-per-lane scatter ----
        const float sx = qsum(ax) + bx;
        gbx = __uint_as_float((unsigned)__builtin_amdgcn_ds_bpermute(
            bpaddr, (int)__float_as_uint(sx)));
    }
}

// ---------------------------------------------------------------------------
// Kernel 3: broadcast batch-0 region to b=1..127 (float4 copy, 17.2 MB write)
// ---------------------------------------------------------------------------
__global__ void bcast_out(const float4* src_base, float4* dst_base) {
    const int TILE = 1056;
    const float4* src = src_base + (blockIdx.x & 7) * TILE;
    float4* dst = dst_base + (size_t)(blockIdx.x + 8) * TILE;   // skip b=0 (8 tiles)
    #pragma unroll 2
    for (int i = threadIdx.x; i < TILE; i += 256) dst[i] = src[i];
}

// ---------------------------------------------------------------------------
extern "C" void kernel_launch(void* const* d_in, const int* in_sizes, int n_in,
                              void* d_out, int out_size, void* d_ws, size_t ws_size,
                              hipStream_t stream) {
    const float* emb  = (const float*)d_in[2];     // row 0 used only
    const float* dWih = (const float*)d_in[7];
    const float* dWhh = (const float*)d_in[8];
    const float* dbih = (const float*)d_in[9];
    const float* dbhh = (const float*)d_in[10];
    const float* fcW  = (const float*)d_in[11];
    const float* fcb  = (const float*)d_in[12];
    float* out = (float*)d_out;

    const size_t need = (size_t)(WT_SZ + WEX_SZ + 256 + 8 + 256 + 8) * sizeof(float);
    float* scratch = (ws_size >= need) ? (float*)d_ws : (out + REGION);
    float* Wt    = scratch;
    float* Wex   = Wt + WT_SZ;
    float* bmain = Wex + WEX_SZ;
    float* bext  = bmain + 256;
    float* g0p   = bext + 8;
    float* g0e   = g0p + 256;

    fold_weights<<<GK, 128, 0, stream>>>(dWih, dWhh, dbih, dbhh, fcW, fcb, emb,
                                         Wt, Wex, bmain, bext, g0p, g0e);
    decode_seq<<<1, 256, 0, stream>>>(Wt, Wex, bmain, bext, g0p, g0e,
                                      out /* b=0 region */);
    bcast_out<<<127 * 8, 256, 0, stream>>>((const float4*)out, (float4*)out);
}